// Round 1
// baseline (234.360 us; speedup 1.0000x reference)
//
#include <hip/hip_runtime.h>

#define FG 15
#define NPROP 512
#define NCLS 16
#define NCI 30   // B*FG
#define SCORE_T 0.05f
#define NMS_T 0.5f
#define DETS 100

__device__ __forceinline__ unsigned sortable_f32(float f) {
  unsigned u = __float_as_uint(f);
  return u ^ ((u >> 31) ? 0xFFFFFFFFu : 0x80000000u);
}

// ---------------- kernel 1: softmax + decode ----------------
__global__ void k_decode(const float* __restrict__ logits,
                         const float* __restrict__ regr,
                         const float* __restrict__ prop,
                         float* __restrict__ score,    // [NCI][NPROP]
                         float* __restrict__ boxes) {  // [NCI][NPROP][5]
#pragma clang fp contract(off)
  int g = blockIdx.x * blockDim.x + threadIdx.x;
  if (g >= 2 * NPROP) return;
  int b = g >> 9, n = g & (NPROP - 1);
  const float* lg = logits + g * NCLS;
  float l[NCLS];
  float mx = -INFINITY;
#pragma unroll
  for (int c = 0; c < NCLS; ++c) { l[c] = lg[c]; mx = fmaxf(mx, l[c]); }
  float e[NCLS];
  float sum = 0.f;
#pragma unroll
  for (int c = 0; c < NCLS; ++c) { e[c] = expf(l[c] - mx); sum += e[c]; }
  const float* pb = prop + g * 5;
  float xc = pb[0], yc = pb[1], w = pb[2], h = pb[3], a = pb[4];
  const float* r = regr + g * 80;
#pragma unroll
  for (int c = 1; c < NCLS; ++c) {
    int ci = b * FG + (c - 1);
    score[ci * NPROP + n] = e[c] / sum;
    float dx = r[c * 5 + 0] / 10.0f;
    float dy = r[c * 5 + 1] / 10.0f;
    float dw = fminf(r[c * 5 + 2] / 5.0f, 4.135166556742356f);
    float dh = fminf(r[c * 5 + 3] / 5.0f, 4.135166556742356f);
    float da = r[c * 5 + 4] / 10.0f;
    float* bo = boxes + (ci * NPROP + n) * 5;
    bo[0] = dx * w + xc;
    bo[1] = dy * h + yc;
    bo[2] = expf(dw) * w;
    bo[3] = expf(dh) * h;
    bo[4] = da * 57.29577951308232f + a;
  }
}

// ---------------- kernel 2: per-class bitonic sort ----------------
__global__ void k_sort(const float* __restrict__ score,
                       const float* __restrict__ boxes,
                       float* __restrict__ ssort,   // [NCI][NPROP] masked, sorted desc
                       float* __restrict__ bsort) { // [NCI][NPROP][5]
  int ci = blockIdx.x;
  __shared__ unsigned long long key[NPROP];
  const float* s = score + ci * NPROP;
  for (int i = threadIdx.x; i < NPROP; i += blockDim.x) {
    float v = s[i];
    float m = (v > SCORE_T) ? v : -INFINITY;
    unsigned so = sortable_f32(m);
    key[i] = ((unsigned long long)(~so) << 32) | (unsigned)i;  // asc key = desc score, asc idx
  }
  __syncthreads();
  for (int k = 2; k <= NPROP; k <<= 1) {
    for (int j = k >> 1; j > 0; j >>= 1) {
      int t = threadIdx.x;  // 256 threads = NPROP/2 pairs
      int i1 = ((t & ~(j - 1)) << 1) | (t & (j - 1));
      int i2 = i1 | j;
      bool up = ((i1 & k) == 0);
      unsigned long long a = key[i1], c = key[i2];
      bool sw = up ? (a > c) : (a < c);
      if (sw) { key[i1] = c; key[i2] = a; }
      __syncthreads();
    }
  }
  for (int i = threadIdx.x; i < NPROP; i += blockDim.x) {
    unsigned long long kv = key[i];
    int idx = (int)(kv & 0xFFFFFFFFull);
    float v = s[idx];
    ssort[ci * NPROP + i] = (v > SCORE_T) ? v : -INFINITY;
    const float* src = boxes + (ci * NPROP + idx) * 5;
    float* dst = bsort + (ci * NPROP + i) * 5;
#pragma unroll
    for (int q = 0; q < 5; ++q) dst[q] = src[q];
  }
}

// ---------------- rotated IoU helpers ----------------
__device__ __forceinline__ void mk_corners(const float* bx, float* X, float* Y) {
#pragma clang fp contract(off)
  float xc = bx[0], yc = bx[1], w = bx[2], h = bx[3], a = bx[4];
  float t = a * 0.017453292519943295f;
  float c = cosf(t), s = sinf(t);
  float hw = w * 0.5f, hh = h * 0.5f;
  float lx[4] = {-hw, hw, hw, -hw};
  float ly[4] = {-hh, -hh, hh, hh};
#pragma unroll
  for (int k = 0; k < 4; ++k) {
    X[k] = xc + lx[k] * c - ly[k] * s;
    Y[k] = yc + lx[k] * s + ly[k] * c;
  }
}

// Sutherland-Hodgman: clip quad A by CCW quad B (same op order as reference).
__device__ float inter_area(const float* Ax, const float* Ay,
                            const float* Bx, const float* By) {
#pragma clang fp contract(off)
  float px[8], py[8];
  int n = 4;
#pragma unroll
  for (int v = 0; v < 4; ++v) { px[v] = Ax[v]; py[v] = Ay[v]; }
  for (int e = 0; e < 4; ++e) {
    float p1x = Bx[e], p1y = By[e];
    int e2 = (e + 1) & 3;
    float ex = Bx[e2] - p1x, ey = By[e2] - p1y;
    float qx[8], qy[8];
    int m = 0;
    for (int v = 0; v < n; ++v) {
      int vn = (v + 1 < n) ? v + 1 : 0;
      float cx = px[v], cy = py[v];
      float nx = px[vn], ny = py[vn];
      float sc = ex * (cy - p1y) - ey * (cx - p1x);
      float sn = ex * (ny - p1y) - ey * (nx - p1x);
      bool ic = sc >= 0.f, inn = sn >= 0.f;
      if (ic && m < 8) { qx[m] = cx; qy[m] = cy; ++m; }
      if ((ic != inn) && m < 8) {
        float den = sc - sn;
        float t = sc / (fabsf(den) > 1e-8f ? den : 1.f);
        qx[m] = cx + t * (nx - cx);
        qy[m] = cy + t * (ny - cy);
        ++m;
      }
    }
    n = m;
    for (int v = 0; v < n; ++v) { px[v] = qx[v]; py[v] = qy[v]; }
    if (n == 0) break;
  }
  if (n < 3) return 0.f;
  float s = 0.f;
  for (int v = 0; v < n; ++v) {
    int vn = (v + 1 < n) ? v + 1 : 0;
    s = s + (px[v] * py[vn] - px[vn] * py[v]);
  }
  return 0.5f * fabsf(s);
}

// ---------------- kernel 3: suppression bitmask ----------------
__global__ void k_mask(const float* __restrict__ ssort,
                       const float* __restrict__ bsort,
                       unsigned long long* __restrict__ mask) { // [NCI][NPROP][8]
#pragma clang fp contract(off)
  int i = blockIdx.x;
  int ci = blockIdx.y;
  int j = threadIdx.x;
  __shared__ float AX[4], AY[4], areaA_s;
  const float* ss = ssort + ci * NPROP;
  float si = ss[i];
  bool vA = si > SCORE_T;
  if (vA && j == 0) {
    const float* bi = bsort + (ci * NPROP + i) * 5;
    mk_corners(bi, AX, AY);
    areaA_s = bi[2] * bi[3];
  }
  __syncthreads();
  bool bit = false;
  if (vA && j > i) {
    float sj = ss[j];
    if (sj > SCORE_T) {
      const float* bj = bsort + (ci * NPROP + j) * 5;
      float BX[4], BY[4];
      mk_corners(bj, BX, BY);
      float ax[4], ay[4];
#pragma unroll
      for (int k = 0; k < 4; ++k) { ax[k] = AX[k]; ay[k] = AY[k]; }
      float inter = inter_area(ax, ay, BX, BY);
      float areaB = bj[2] * bj[3];
      float uni = (areaA_s + areaB) - inter;
      float iou = inter / fmaxf(uni, 1e-8f);
      bit = iou > NMS_T;
    }
  }
  unsigned long long bal = __ballot(bit);
  if ((j & 63) == 0) mask[(ci * NPROP + i) * 8 + (j >> 6)] = bal;
}

// ---------------- kernel 4: greedy bitmask NMS scan ----------------
__global__ void k_nms(const float* __restrict__ ssort,
                      const unsigned long long* __restrict__ mask,
                      float* __restrict__ kept) {  // [NCI][NPROP]
  int ci = blockIdx.x;
  __shared__ unsigned long long lmask[NPROP * 8];  // 32 KiB
  __shared__ unsigned long long keptw[8];
  __shared__ int vcnt;
  const float* ss = ssort + ci * NPROP;
  if (threadIdx.x == 0) vcnt = NPROP;
  if (threadIdx.x < 8) keptw[threadIdx.x] = 0ull;
  __syncthreads();
  for (int i = threadIdx.x; i < NPROP; i += blockDim.x)
    if (!(ss[i] > SCORE_T)) atomicMin(&vcnt, i);
  __syncthreads();
  int V = vcnt;
  for (int x = threadIdx.x; x < V * 8; x += blockDim.x)
    lmask[x] = mask[(ci * NPROP) * 8 + x];
  __syncthreads();
  if (threadIdx.x < 64) {
    int lane = threadIdx.x;
    unsigned long long removed = 0ull, kb = 0ull;
    int kc = 0;
    for (int i = 0; i < V; ++i) {
      int w = i >> 6, bp = i & 63;
      unsigned long long rw = __shfl(removed, w);
      if (!((rw >> bp) & 1ull)) {
        if (lane == w) kb |= (1ull << bp);
        if (lane < 8) removed |= lmask[i * 8 + lane];
        if (++kc >= DETS) break;  // first 100 kept fully determine output
      }
    }
    if (lane < 8) keptw[lane] = kb;
  }
  __syncthreads();
  for (int i = threadIdx.x; i < NPROP; i += blockDim.x) {
    bool k = (keptw[i >> 6] >> (i & 63)) & 1ull;
    kept[ci * NPROP + i] = k ? ss[i] : -INFINITY;
  }
}

// ---------------- kernel 5: cross-class top-100 + output ----------------
__global__ void k_topk(const float* __restrict__ kept,
                       const float* __restrict__ bsort,
                       float* __restrict__ out) {
  int b = blockIdx.x;
  __shared__ unsigned long long list[2048];
  __shared__ int cnt;
  if (threadIdx.x == 0) cnt = 0;
  for (int i = threadIdx.x; i < 2048; i += blockDim.x) list[i] = 0ull;
  __syncthreads();
  const float* ks = kept + b * FG * NPROP;
  for (int i = threadIdx.x; i < FG * NPROP; i += blockDim.x) {
    float s = ks[i];
    if (s > 0.f) {  // kept scores are > 0.05; -inf otherwise
      unsigned key_hi = __float_as_uint(s) ^ 0x80000000u;  // s > 0
      unsigned long long key =
          ((unsigned long long)key_hi << 32) | (unsigned)(~i);  // ties: lower i wins
      int p = atomicAdd(&cnt, 1);
      list[p] = key;
    }
  }
  __syncthreads();
  for (int k = 2; k <= 2048; k <<= 1) {
    for (int j = k >> 1; j > 0; j >>= 1) {
      for (int t = threadIdx.x; t < 1024; t += blockDim.x) {
        int i1 = ((t & ~(j - 1)) << 1) | (t & (j - 1));
        int i2 = i1 | j;
        bool up = ((i1 & k) == 0);
        unsigned long long a = list[i1], c = list[i2];
        bool sw = up ? (a < c) : (a > c);  // descending sort
        if (sw) { list[i1] = c; list[i2] = a; }
      }
      __syncthreads();
    }
  }
  if (threadIdx.x < DETS) {
    int r = threadIdx.x;
    float* o = out + (b * DETS + r) * 6;
    unsigned long long key = list[r];
    if (key == 0ull) {
#pragma unroll
      for (int q = 0; q < 6; ++q) o[q] = 0.f;
    } else {
      int flat = (int)(~(unsigned)(key & 0xFFFFFFFFull));
      const float* bx = bsort + (b * FG * NPROP + flat) * 5;
#pragma unroll
      for (int q = 0; q < 5; ++q) o[q] = bx[q];
      o[5] = ks[flat];
    }
  }
}

extern "C" void kernel_launch(void* const* d_in, const int* in_sizes, int n_in,
                              void* d_out, int out_size, void* d_ws, size_t ws_size,
                              hipStream_t stream) {
  const float* logits = (const float*)d_in[0];
  const float* regr   = (const float*)d_in[1];
  const float* prop   = (const float*)d_in[2];
  float* out = (float*)d_out;

  float* score = (float*)d_ws;                 // NCI*NPROP
  float* boxes = score + NCI * NPROP;          // NCI*NPROP*5
  float* ssort = boxes + NCI * NPROP * 5;      // NCI*NPROP
  float* bsort = ssort + NCI * NPROP;          // NCI*NPROP*5
  float* kept  = bsort + NCI * NPROP * 5;      // NCI*NPROP
  unsigned long long* mask =
      (unsigned long long*)(kept + NCI * NPROP);  // NCI*NPROP*8 u64 (offset 798720 B, 8-aligned)

  hipLaunchKernelGGL(k_decode, dim3(4), dim3(256), 0, stream, logits, regr, prop, score, boxes);
  hipLaunchKernelGGL(k_sort, dim3(NCI), dim3(256), 0, stream, score, boxes, ssort, bsort);
  hipLaunchKernelGGL(k_mask, dim3(NPROP, NCI), dim3(NPROP), 0, stream, ssort, bsort, mask);
  hipLaunchKernelGGL(k_nms, dim3(NCI), dim3(256), 0, stream, ssort, mask, kept);
  hipLaunchKernelGGL(k_topk, dim3(2), dim3(256), 0, stream, kept, bsort, out);
}

// Round 2
// 163.690 us; speedup vs baseline: 1.4317x; 1.4317x over previous
//
#include <hip/hip_runtime.h>

#define FG 15
#define NPROP 512
#define NCLS 16
#define NCI 30   // B*FG
#define SCORE_T 0.05f
#define NMS_T 0.5f
#define DETS 100

__device__ __forceinline__ unsigned sortable_f32(float f) {
  unsigned u = __float_as_uint(f);
  return u ^ ((u >> 31) ? 0xFFFFFFFFu : 0x80000000u);
}

// ---------------- kernel 1: softmax + decode ----------------
__global__ void k_decode(const float* __restrict__ logits,
                         const float* __restrict__ regr,
                         const float* __restrict__ prop,
                         float* __restrict__ score,    // [NCI][NPROP]
                         float* __restrict__ boxes) {  // [NCI][NPROP][5]
#pragma clang fp contract(off)
  int g = blockIdx.x * blockDim.x + threadIdx.x;
  if (g >= 2 * NPROP) return;
  int b = g >> 9, n = g & (NPROP - 1);
  const float* lg = logits + g * NCLS;
  float l[NCLS];
  float mx = -INFINITY;
#pragma unroll
  for (int c = 0; c < NCLS; ++c) { l[c] = lg[c]; mx = fmaxf(mx, l[c]); }
  float e[NCLS];
  float sum = 0.f;
#pragma unroll
  for (int c = 0; c < NCLS; ++c) { e[c] = expf(l[c] - mx); sum += e[c]; }
  const float* pb = prop + g * 5;
  float xc = pb[0], yc = pb[1], w = pb[2], h = pb[3], a = pb[4];
  const float* r = regr + g * 80;
#pragma unroll
  for (int c = 1; c < NCLS; ++c) {
    int ci = b * FG + (c - 1);
    score[ci * NPROP + n] = e[c] / sum;
    float dx = r[c * 5 + 0] / 10.0f;
    float dy = r[c * 5 + 1] / 10.0f;
    float dw = fminf(r[c * 5 + 2] / 5.0f, 4.135166556742356f);
    float dh = fminf(r[c * 5 + 3] / 5.0f, 4.135166556742356f);
    float da = r[c * 5 + 4] / 10.0f;
    float* bo = boxes + (ci * NPROP + n) * 5;
    bo[0] = dx * w + xc;
    bo[1] = dy * h + yc;
    bo[2] = expf(dw) * w;
    bo[3] = expf(dh) * h;
    bo[4] = da * 57.29577951308232f + a;
  }
}

__device__ __forceinline__ void mk_corners(const float* bx, float* X, float* Y) {
#pragma clang fp contract(off)
  float xc = bx[0], yc = bx[1], w = bx[2], h = bx[3], a = bx[4];
  float t = a * 0.017453292519943295f;
  float c = cosf(t), s = sinf(t);
  float hw = w * 0.5f, hh = h * 0.5f;
  float lx[4] = {-hw, hw, hw, -hw};
  float ly[4] = {-hh, -hh, hh, hh};
#pragma unroll
  for (int k = 0; k < 4; ++k) {
    X[k] = xc + lx[k] * c - ly[k] * s;
    Y[k] = yc + lx[k] * s + ly[k] * c;
  }
}

// ---------------- kernel 2: per-class bitonic sort + corner precompute ----------------
__global__ void k_sort(const float* __restrict__ score,
                       const float* __restrict__ boxes,
                       float* __restrict__ ssort,   // [NCI][NPROP] masked, sorted desc
                       float* __restrict__ bsort,   // [NCI][NPROP][5]
                       float* __restrict__ csort,   // [NCI][NPROP][8] corners x0..x3,y0..y3
                       float* __restrict__ areas) { // [NCI][NPROP]
  int ci = blockIdx.x;
  __shared__ unsigned long long key[NPROP];
  const float* s = score + ci * NPROP;
  for (int i = threadIdx.x; i < NPROP; i += blockDim.x) {
    float v = s[i];
    float m = (v > SCORE_T) ? v : -INFINITY;
    unsigned so = sortable_f32(m);
    key[i] = ((unsigned long long)(~so) << 32) | (unsigned)i;  // asc key = desc score, asc idx
  }
  __syncthreads();
  for (int k = 2; k <= NPROP; k <<= 1) {
    for (int j = k >> 1; j > 0; j >>= 1) {
      int t = threadIdx.x;  // 256 threads = NPROP/2 pairs
      int i1 = ((t & ~(j - 1)) << 1) | (t & (j - 1));
      int i2 = i1 | j;
      bool up = ((i1 & k) == 0);
      unsigned long long a = key[i1], c = key[i2];
      bool sw = up ? (a > c) : (a < c);
      if (sw) { key[i1] = c; key[i2] = a; }
      __syncthreads();
    }
  }
  for (int i = threadIdx.x; i < NPROP; i += blockDim.x) {
    unsigned long long kv = key[i];
    int idx = (int)(kv & 0xFFFFFFFFull);
    float v = s[idx];
    ssort[ci * NPROP + i] = (v > SCORE_T) ? v : -INFINITY;
    const float* src = boxes + (ci * NPROP + idx) * 5;
    float bb[5];
#pragma unroll
    for (int q = 0; q < 5; ++q) bb[q] = src[q];
    float* dst = bsort + (ci * NPROP + i) * 5;
#pragma unroll
    for (int q = 0; q < 5; ++q) dst[q] = bb[q];
    float X[4], Y[4];
    mk_corners(bb, X, Y);
    float* cd = csort + (ci * NPROP + i) * 8;
#pragma unroll
    for (int k = 0; k < 4; ++k) { cd[k] = X[k]; cd[4 + k] = Y[k]; }
    areas[ci * NPROP + i] = bb[2] * bb[3];
  }
}

// ---------------- register-resident Sutherland-Hodgman ----------------
// All trip counts compile-time; n only appears in predicates. Scatter caps at
// 8 slots and n clamps to 8 — identical overflow semantics to the reference's
// [:MAXV] truncation.
template<int NIN>
__device__ __forceinline__ int clip_edge_reg(const float (&inx)[9], const float (&iny)[9],
                                             int n, float p1x, float p1y,
                                             float ex, float ey,
                                             float (&ox)[9], float (&oy)[9]) {
#pragma clang fp contract(off)
  int m = 0;
#pragma unroll
  for (int o = 0; o < 9; ++o) { ox[o] = 0.f; oy[o] = 0.f; }
#pragma unroll
  for (int v = 0; v < NIN; ++v) {
    bool valid = v < n;
    bool wrap = (v + 1 >= n);
    float cx = inx[v], cy = iny[v];
    float nx = wrap ? inx[0] : inx[v + 1];
    float ny = wrap ? iny[0] : iny[v + 1];
    float sc = ex * (cy - p1y) - ey * (cx - p1x);
    float sn = ex * (ny - p1y) - ey * (nx - p1x);
    bool ic = sc >= 0.f;
    bool inn = sn >= 0.f;
    float den = sc - sn;
    float tt = sc / (fabsf(den) > 1e-8f ? den : 1.f);
    float qx = cx + tt * (nx - cx);
    float qy = cy + tt * (ny - cy);
    bool fC = valid && ic;
    bool fI = valid && (ic != inn);
#pragma unroll
    for (int o = 0; o < 8; ++o) {
      bool w = fC && (m == o);
      ox[o] = w ? cx : ox[o];
      oy[o] = w ? cy : oy[o];
    }
    m += fC ? 1 : 0;
#pragma unroll
    for (int o = 0; o < 8; ++o) {
      bool w = fI && (m == o);
      ox[o] = w ? qx : ox[o];
      oy[o] = w ? qy : oy[o];
    }
    m += fI ? 1 : 0;
  }
  return (m < 8) ? m : 8;
}

__device__ __forceinline__ float poly_area(const float (&px)[9], const float (&py)[9], int n) {
#pragma clang fp contract(off)
  float s = 0.f;
#pragma unroll
  for (int v = 0; v < 8; ++v) {
    bool valid = v < n;
    bool wrap = (v + 1 >= n);
    float ax = px[v], ay = py[v];
    float bx = wrap ? px[0] : px[v + 1];
    float by = wrap ? py[0] : py[v + 1];
    float cr = ax * by - bx * ay;
    s = s + (valid ? cr : 0.f);
  }
  float area = 0.5f * fabsf(s);
  return (n >= 3) ? area : 0.f;
}

__device__ __forceinline__ float inter_area_reg(const float (&Ax)[4], const float (&Ay)[4],
                                                const float (&Bx)[4], const float (&By)[4]) {
#pragma clang fp contract(off)
  float s0x[9], s0y[9];
#pragma unroll
  for (int v = 0; v < 9; ++v) { s0x[v] = 0.f; s0y[v] = 0.f; }
#pragma unroll
  for (int v = 0; v < 4; ++v) { s0x[v] = Ax[v]; s0y[v] = Ay[v]; }
  float s1x[9], s1y[9], s2x[9], s2y[9], s3x[9], s3y[9], s4x[9], s4y[9];
  int n = 4;
  n = clip_edge_reg<4>(s0x, s0y, n, Bx[0], By[0], Bx[1] - Bx[0], By[1] - By[0], s1x, s1y);
  n = clip_edge_reg<8>(s1x, s1y, n, Bx[1], By[1], Bx[2] - Bx[1], By[2] - By[1], s2x, s2y);
  n = clip_edge_reg<8>(s2x, s2y, n, Bx[2], By[2], Bx[3] - Bx[2], By[3] - By[2], s3x, s3y);
  n = clip_edge_reg<8>(s3x, s3y, n, Bx[3], By[3], Bx[0] - Bx[3], By[0] - By[3], s4x, s4y);
  return poly_area(s4x, s4y, n);
}

// ---------------- kernel 3: suppression bitmask ----------------
__global__ void __launch_bounds__(512) k_mask(const float* __restrict__ ssort,
                                              const float* __restrict__ csort,
                                              const float* __restrict__ areas,
                                              unsigned long long* __restrict__ mask) {
#pragma clang fp contract(off)
  int i = blockIdx.x;
  int ci = blockIdx.y;
  int j = threadIdx.x;
  const float* ss = ssort + ci * NPROP;
  float si = ss[i];
  bool bit = false;
  if (si > SCORE_T && j > i) {
    float sj = ss[j];
    if (sj > SCORE_T) {
      const float* ca = csort + (ci * NPROP + i) * 8;
      const float* cb = csort + (ci * NPROP + j) * 8;
      float Ax[4], Ay[4], Bx[4], By[4];
#pragma unroll
      for (int k = 0; k < 4; ++k) {
        Ax[k] = ca[k]; Ay[k] = ca[4 + k];
        Bx[k] = cb[k]; By[k] = cb[4 + k];
      }
      float inter = inter_area_reg(Ax, Ay, Bx, By);
      float areaA = areas[ci * NPROP + i];
      float areaB = areas[ci * NPROP + j];
      float uni = (areaA + areaB) - inter;
      float iou = inter / fmaxf(uni, 1e-8f);
      bit = iou > NMS_T;
    }
  }
  unsigned long long bal = __ballot(bit);
  if ((j & 63) == 0) mask[(ci * NPROP + i) * 8 + (j >> 6)] = bal;
}

// ---------------- kernel 4: greedy bitmask NMS scan ----------------
__global__ void k_nms(const float* __restrict__ ssort,
                      const unsigned long long* __restrict__ mask,
                      float* __restrict__ kept) {  // [NCI][NPROP]
  int ci = blockIdx.x;
  __shared__ unsigned long long lmask[NPROP * 8];  // 32 KiB
  __shared__ unsigned long long keptw[8];
  __shared__ int vcnt;
  const float* ss = ssort + ci * NPROP;
  if (threadIdx.x == 0) vcnt = NPROP;
  if (threadIdx.x < 8) keptw[threadIdx.x] = 0ull;
  __syncthreads();
  for (int i = threadIdx.x; i < NPROP; i += blockDim.x)
    if (!(ss[i] > SCORE_T)) atomicMin(&vcnt, i);
  __syncthreads();
  int V = vcnt;
  for (int x = threadIdx.x; x < V * 8; x += blockDim.x)
    lmask[x] = mask[(ci * NPROP) * 8 + x];
  __syncthreads();
  if (threadIdx.x < 64) {
    int lane = threadIdx.x;
    unsigned long long removed = 0ull, kb = 0ull;
    int kc = 0;
    for (int i = 0; i < V; ++i) {
      int w = i >> 6, bp = i & 63;
      unsigned long long rw = __shfl(removed, w);
      if (!((rw >> bp) & 1ull)) {
        if (lane == w) kb |= (1ull << bp);
        if (lane < 8) removed |= lmask[i * 8 + lane];
        if (++kc >= DETS) break;  // first 100 kept fully determine output
      }
    }
    if (lane < 8) keptw[lane] = kb;
  }
  __syncthreads();
  for (int i = threadIdx.x; i < NPROP; i += blockDim.x) {
    bool k = (keptw[i >> 6] >> (i & 63)) & 1ull;
    kept[ci * NPROP + i] = k ? ss[i] : -INFINITY;
  }
}

// ---------------- kernel 5: cross-class top-100 + output ----------------
__global__ void k_topk(const float* __restrict__ kept,
                       const float* __restrict__ bsort,
                       float* __restrict__ out) {
  int b = blockIdx.x;
  __shared__ unsigned long long list[2048];
  __shared__ int cnt;
  if (threadIdx.x == 0) cnt = 0;
  for (int i = threadIdx.x; i < 2048; i += blockDim.x) list[i] = 0ull;
  __syncthreads();
  const float* ks = kept + b * FG * NPROP;
  for (int i = threadIdx.x; i < FG * NPROP; i += blockDim.x) {
    float s = ks[i];
    if (s > 0.f) {  // kept scores are > 0.05; -inf otherwise
      unsigned key_hi = __float_as_uint(s) ^ 0x80000000u;  // s > 0
      unsigned long long key =
          ((unsigned long long)key_hi << 32) | (unsigned)(~i);  // ties: lower i wins
      int p = atomicAdd(&cnt, 1);
      list[p] = key;
    }
  }
  __syncthreads();
  for (int k = 2; k <= 2048; k <<= 1) {
    for (int j = k >> 1; j > 0; j >>= 1) {
      for (int t = threadIdx.x; t < 1024; t += blockDim.x) {
        int i1 = ((t & ~(j - 1)) << 1) | (t & (j - 1));
        int i2 = i1 | j;
        bool up = ((i1 & k) == 0);
        unsigned long long a = list[i1], c = list[i2];
        bool sw = up ? (a < c) : (a > c);  // descending sort
        if (sw) { list[i1] = c; list[i2] = a; }
      }
      __syncthreads();
    }
  }
  if (threadIdx.x < DETS) {
    int r = threadIdx.x;
    float* o = out + (b * DETS + r) * 6;
    unsigned long long key = list[r];
    if (key == 0ull) {
#pragma unroll
      for (int q = 0; q < 6; ++q) o[q] = 0.f;
    } else {
      int flat = (int)(~(unsigned)(key & 0xFFFFFFFFull));
      const float* bx = bsort + (b * FG * NPROP + flat) * 5;
#pragma unroll
      for (int q = 0; q < 5; ++q) o[q] = bx[q];
      o[5] = ks[flat];
    }
  }
}

extern "C" void kernel_launch(void* const* d_in, const int* in_sizes, int n_in,
                              void* d_out, int out_size, void* d_ws, size_t ws_size,
                              hipStream_t stream) {
  const float* logits = (const float*)d_in[0];
  const float* regr   = (const float*)d_in[1];
  const float* prop   = (const float*)d_in[2];
  float* out = (float*)d_out;

  float* score = (float*)d_ws;                 // NCI*NPROP
  float* boxes = score + NCI * NPROP;          // NCI*NPROP*5
  float* ssort = boxes + NCI * NPROP * 5;      // NCI*NPROP
  float* bsort = ssort + NCI * NPROP;          // NCI*NPROP*5
  float* kept  = bsort + NCI * NPROP * 5;      // NCI*NPROP
  float* csort = kept + NCI * NPROP;           // NCI*NPROP*8
  float* areas = csort + NCI * NPROP * 8;      // NCI*NPROP
  unsigned long long* mask =
      (unsigned long long*)(areas + NCI * NPROP);  // NCI*NPROP*8 u64, 8B-aligned

  hipLaunchKernelGGL(k_decode, dim3(4), dim3(256), 0, stream, logits, regr, prop, score, boxes);
  hipLaunchKernelGGL(k_sort, dim3(NCI), dim3(256), 0, stream, score, boxes, ssort, bsort, csort, areas);
  hipLaunchKernelGGL(k_mask, dim3(NPROP, NCI), dim3(NPROP), 0, stream, ssort, csort, areas, mask);
  hipLaunchKernelGGL(k_nms, dim3(NCI), dim3(256), 0, stream, ssort, mask, kept);
  hipLaunchKernelGGL(k_topk, dim3(2), dim3(256), 0, stream, kept, bsort, out);
}